// Round 1
// baseline (6976.117 us; speedup 1.0000x reference)
//
#include <hip/hip_runtime.h>

#define NCLS 64
#define ALPHA 0.9f

__device__ __forceinline__ float wave_max64(float v) {
    #pragma unroll
    for (int o = 32; o > 0; o >>= 1) v = fmaxf(v, __shfl_xor(v, o, 64));
    return v;
}
__device__ __forceinline__ float wave_sum64(float v) {
    #pragma unroll
    for (int o = 32; o > 0; o >>= 1) v += __shfl_xor(v, o, 64);
    return v;
}

// One 64-lane wave per row: softmax over C=64 classes.
__global__ void softmax_k(const float* __restrict__ y, float* __restrict__ z, int n_nodes) {
    int lane = threadIdx.x & 63;
    int wave = (blockIdx.x * blockDim.x + threadIdx.x) >> 6;
    int nwaves = (gridDim.x * blockDim.x) >> 6;
    for (int n = wave; n < n_nodes; n += nwaves) {
        float v = y[(size_t)n * NCLS + lane];
        float m = wave_max64(v);
        float e = expf(v - m);
        float s = wave_sum64(e);
        z[(size_t)n * NCLS + lane] = e / s;
    }
}

// Deterministic "last write wins" for duplicate mask entries: winner[node] = max i.
__global__ void winner_k(const int* __restrict__ mask, int* __restrict__ winner, int L) {
    int i = blockIdx.x * blockDim.x + threadIdx.x;
    if (i < L) atomicMax(&winner[mask[i]], i);
}

// One wave per labeled entry; the winning entry writes its one-hot row.
__global__ void clamp_k(const int* __restrict__ mask, const int* __restrict__ ytrue,
                        const int* __restrict__ winner, float* __restrict__ out, int L) {
    int lane = threadIdx.x & 63;
    int wv = (blockIdx.x * blockDim.x + threadIdx.x) >> 6;
    if (wv < L) {
        int m = mask[wv];
        if (winner[m] == wv) {
            out[(size_t)m * NCLS + lane] = (lane == ytrue[wv]) ? 1.0f : 0.0f;
        }
    }
}

__global__ void deg_k(const int* __restrict__ col, int* __restrict__ deg, int E) {
    int stride = gridDim.x * blockDim.x;
    for (int e = blockIdx.x * blockDim.x + threadIdx.x; e < E; e += stride)
        atomicAdd(&deg[col[e]], 1);
}

__global__ void dinv_k(const int* __restrict__ deg, float* __restrict__ dinv, int n_nodes) {
    int i = blockIdx.x * blockDim.x + threadIdx.x;
    if (i < n_nodes) {
        int d = deg[i];
        dinv[i] = (d > 0) ? rsqrtf((float)d) : 0.0f;
    }
}

__global__ void norm_k(const int* __restrict__ row, const int* __restrict__ col,
                       const float* __restrict__ dinv, float* __restrict__ norm, int E) {
    int stride = gridDim.x * blockDim.x;
    for (int e = blockIdx.x * blockDim.x + threadIdx.x; e < E; e += stride)
        norm[e] = dinv[row[e]] * dinv[col[e]];
}

__global__ void res_k(const float4* __restrict__ out, float4* __restrict__ res, int n4) {
    int stride = gridDim.x * blockDim.x;
    const float ra = 1.0f - ALPHA;
    for (int i = blockIdx.x * blockDim.x + threadIdx.x; i < n4; i += stride) {
        float4 o = out[i];
        float4 r;
        r.x = ra * o.x; r.y = ra * o.y; r.z = ra * o.z; r.w = ra * o.w;
        res[i] = r;
    }
}

// One wave per edge (lane = class): msg = norm[e] * out[row[e]][lane],
// atomically accumulated into agg[col[e]][lane].
__global__ void edge_k(const int* __restrict__ row, const int* __restrict__ col,
                       const float* __restrict__ norm, const float* __restrict__ out,
                       float* __restrict__ agg, int E) {
    int lane = threadIdx.x & 63;
    int wave = (blockIdx.x * blockDim.x + threadIdx.x) >> 6;
    int nwaves = (gridDim.x * blockDim.x) >> 6;
    for (int e = wave; e < E; e += nwaves) {
        int r = row[e];
        int c = col[e];
        float w = norm[e];
        float v = w * out[(size_t)r * NCLS + lane];
        atomicAdd(&agg[(size_t)c * NCLS + lane], v);
    }
}

__global__ void update_k(const float4* __restrict__ agg, const float4* __restrict__ res,
                         float4* __restrict__ out, int n4) {
    int stride = gridDim.x * blockDim.x;
    for (int i = blockIdx.x * blockDim.x + threadIdx.x; i < n4; i += stride) {
        float4 a = agg[i];
        float4 r = res[i];
        float4 o;
        o.x = fminf(fmaxf(ALPHA * a.x + r.x, 0.0f), 1.0f);
        o.y = fminf(fmaxf(ALPHA * a.y + r.y, 0.0f), 1.0f);
        o.z = fminf(fmaxf(ALPHA * a.z + r.z, 0.0f), 1.0f);
        o.w = fminf(fmaxf(ALPHA * a.w + r.w, 0.0f), 1.0f);
        out[i] = o;
    }
}

extern "C" void kernel_launch(void* const* d_in, const int* in_sizes, int n_in,
                              void* d_out, int out_size, void* d_ws, size_t ws_size,
                              hipStream_t stream) {
    const float* y_soft = (const float*)d_in[0];
    const int* y_true  = (const int*)d_in[1];
    const int* mask    = (const int*)d_in[2];
    const int* edge    = (const int*)d_in[3];

    const int NC = in_sizes[0];          // N * C
    const int Nn = NC / NCLS;            // N
    const int L  = in_sizes[1];
    const int E  = in_sizes[3] / 2;

    const int* row = edge;               // edge_index[0] = source
    const int* col = edge + E;           // edge_index[1] = target

    float* out = (float*)d_out;

    char* ws = (char*)d_ws;
    float* res  = (float*)ws;                              // N*C f32
    float* agg  = (float*)(ws + (size_t)NC * 4);           // N*C f32
    float* nrm  = (float*)(ws + (size_t)NC * 8);           // E f32
    // Setup-phase scratch aliases the agg region (agg is only live in the loop):
    int*   deg    = (int*)agg;
    float* dinv   = (float*)agg + Nn;
    int*   winner = (int*)agg + 2 * (size_t)Nn;

    hipMemsetAsync(deg, 0, (size_t)Nn * 4, stream);
    hipMemsetAsync(winner, 0xFF, (size_t)Nn * 4, stream);  // -1

    softmax_k<<<2048, 256, 0, stream>>>(y_soft, out, Nn);
    winner_k<<<(L + 255) / 256, 256, 0, stream>>>(mask, winner, L);
    clamp_k<<<(L * 64 + 255) / 256, 256, 0, stream>>>(mask, y_true, winner, out, L);
    deg_k<<<2048, 256, 0, stream>>>(col, deg, E);
    dinv_k<<<(Nn + 255) / 256, 256, 0, stream>>>(deg, dinv, Nn);
    norm_k<<<2048, 256, 0, stream>>>(row, col, dinv, nrm, E);
    res_k<<<2048, 256, 0, stream>>>((const float4*)out, (float4*)res, NC / 4);

    for (int it = 0; it < 10; ++it) {
        hipMemsetAsync(agg, 0, (size_t)NC * 4, stream);
        edge_k<<<2048, 256, 0, stream>>>(row, col, nrm, out, agg, E);
        update_k<<<2048, 256, 0, stream>>>((const float4*)agg, (const float4*)res,
                                           (float4*)out, NC / 4);
    }
}

// Round 2
// 1626.571 us; speedup vs baseline: 4.2888x; 4.2888x over previous
//
#include <hip/hip_runtime.h>
#include <hip/hip_fp16.h>

#define NCLS 64
#define ALPHA 0.9f
#define SCAN_BS 256
#define SCAN_CHUNK 1024   // SCAN_BS * 4 items/thread

__device__ __forceinline__ float wave_max64(float v) {
    #pragma unroll
    for (int o = 32; o > 0; o >>= 1) v = fmaxf(v, __shfl_xor(v, o, 64));
    return v;
}
__device__ __forceinline__ float wave_sum64(float v) {
    #pragma unroll
    for (int o = 32; o > 0; o >>= 1) v += __shfl_xor(v, o, 64);
    return v;
}

// One 64-lane wave per row: softmax over C=64 classes. Writes u = softmax(y).
__global__ void softmax_k(const float* __restrict__ y, float* __restrict__ u, int n_nodes) {
    int lane = threadIdx.x & 63;
    int wave = (blockIdx.x * blockDim.x + threadIdx.x) >> 6;
    int nwaves = (gridDim.x * blockDim.x) >> 6;
    for (int n = wave; n < n_nodes; n += nwaves) {
        float v = y[(size_t)n * NCLS + lane];
        float m = wave_max64(v);
        float e = expf(v - m);
        float s = wave_sum64(e);
        u[(size_t)n * NCLS + lane] = e / s;
    }
}

// Deterministic "last write wins" for duplicate mask entries: winner[node] = max i.
__global__ void winner_k(const int* __restrict__ mask, int* __restrict__ winner, int L) {
    int i = blockIdx.x * blockDim.x + threadIdx.x;
    if (i < L) atomicMax(&winner[mask[i]], i);
}

// One wave per labeled entry; the winning entry writes its one-hot row into u.
__global__ void clamp_k(const int* __restrict__ mask, const int* __restrict__ ytrue,
                        const int* __restrict__ winner, float* __restrict__ u, int L) {
    int lane = threadIdx.x & 63;
    int wv = (blockIdx.x * blockDim.x + threadIdx.x) >> 6;
    if (wv < L) {
        int m = mask[wv];
        if (winner[m] == wv) {
            u[(size_t)m * NCLS + lane] = (lane == ytrue[wv]) ? 1.0f : 0.0f;
        }
    }
}

__global__ void deg_k(const int* __restrict__ col, int* __restrict__ deg, int E) {
    int stride = gridDim.x * blockDim.x;
    for (int e = blockIdx.x * blockDim.x + threadIdx.x; e < E; e += stride)
        atomicAdd(&deg[col[e]], 1);
}

__global__ void dinv_k(const int* __restrict__ deg, float* __restrict__ dinv, int n_nodes) {
    int i = blockIdx.x * blockDim.x + threadIdx.x;
    if (i < n_nodes) {
        int d = deg[i];
        dinv[i] = (d > 0) ? rsqrtf((float)d) : 0.0f;
    }
}

// ---- exclusive scan of deg -> rowptr (3 kernels, N up to 256*1024) ----
__global__ void scan_local_k(const int* __restrict__ deg, int* __restrict__ rowptr,
                             int* __restrict__ bsum, int n) {
    __shared__ int lds[SCAN_BS];
    int base = blockIdx.x * SCAN_CHUNK;
    int t = threadIdx.x;
    int v[4];
    int s = 0;
    #pragma unroll
    for (int k = 0; k < 4; ++k) {
        int i = base + t * 4 + k;
        v[k] = (i < n) ? deg[i] : 0;
        s += v[k];
    }
    lds[t] = s;
    __syncthreads();
    for (int o = 1; o < SCAN_BS; o <<= 1) {
        int x = (t >= o) ? lds[t - o] : 0;
        __syncthreads();
        lds[t] += x;
        __syncthreads();
    }
    int ex = (t > 0) ? lds[t - 1] : 0;
    #pragma unroll
    for (int k = 0; k < 4; ++k) {
        int i = base + t * 4 + k;
        if (i < n) rowptr[i] = ex;
        ex += v[k];
    }
    if (t == SCAN_BS - 1) bsum[blockIdx.x] = lds[t];
}

__global__ void scan_bsum_k(int* __restrict__ bsum, int nb) {
    __shared__ int lds[SCAN_BS];
    int t = threadIdx.x;
    int v = (t < nb) ? bsum[t] : 0;
    lds[t] = v;
    __syncthreads();
    for (int o = 1; o < SCAN_BS; o <<= 1) {
        int x = (t >= o) ? lds[t - o] : 0;
        __syncthreads();
        lds[t] += x;
        __syncthreads();
    }
    if (t < nb) bsum[t] = lds[t] - v;   // exclusive
}

__global__ void scan_add_k(int* __restrict__ rowptr, const int* __restrict__ bsum, int n) {
    int i = blockIdx.x * blockDim.x + threadIdx.x;
    if (i < n) rowptr[i] += bsum[i / SCAN_CHUNK];
}

__global__ void copy_int_k(const int* __restrict__ a, int* __restrict__ b, int n) {
    int i = blockIdx.x * blockDim.x + threadIdx.x;
    if (i < n) b[i] = a[i];
}

// Counting-sort scatter: src[pos] = row[e], grouped by destination col[e].
__global__ void scatter_k(const int* __restrict__ row, const int* __restrict__ col,
                          int* __restrict__ cursor, int* __restrict__ src, int E) {
    int stride = gridDim.x * blockDim.x;
    for (int e = blockIdx.x * blockDim.x + threadIdx.x; e < E; e += stride) {
        int p = atomicAdd(&cursor[col[e]], 1);
        src[p] = row[e];
    }
}

// res_h = (1-alpha)*u (fp16), and u -> v = dinv*u in place.
__global__ void vres_k(const float* __restrict__ dinv, float* __restrict__ u,
                       __half* __restrict__ res_h, int nc) {
    int stride = gridDim.x * blockDim.x;
    for (int i = blockIdx.x * blockDim.x + threadIdx.x; i < nc; i += stride) {
        float uu = u[i];
        res_h[i] = __float2half((1.0f - ALPHA) * uu);
        u[i] = dinv[i >> 6] * uu;
    }
}

// Fused pull + update: one wave per node, lane = class.
// vin holds v = dinv*u; writes v_next (or u_next if last).
__global__ void pull_k(const int* __restrict__ rowptr, const int* __restrict__ deg,
                       const int* __restrict__ src, const float* __restrict__ dinv,
                       const float* __restrict__ vin, const __half* __restrict__ res_h,
                       float* __restrict__ vout, int n_nodes, int last) {
    int lane = threadIdx.x & 63;
    int n = (blockIdx.x * blockDim.x + threadIdx.x) >> 6;
    if (n >= n_nodes) return;
    int start = rowptr[n];
    int len = deg[n];
    float acc = 0.0f;
    int j = 0;
    for (; j + 4 <= len; j += 4) {
        int s0 = src[start + j];
        int s1 = src[start + j + 1];
        int s2 = src[start + j + 2];
        int s3 = src[start + j + 3];
        float a0 = vin[(size_t)s0 * NCLS + lane];
        float a1 = vin[(size_t)s1 * NCLS + lane];
        float a2 = vin[(size_t)s2 * NCLS + lane];
        float a3 = vin[(size_t)s3 * NCLS + lane];
        acc += (a0 + a1) + (a2 + a3);
    }
    for (; j < len; ++j)
        acc += vin[(size_t)src[start + j] * NCLS + lane];
    float di = dinv[n];
    float u = ALPHA * (di * acc) + __half2float(res_h[(size_t)n * NCLS + lane]);
    u = fminf(fmaxf(u, 0.0f), 1.0f);
    vout[(size_t)n * NCLS + lane] = last ? u : di * u;
}

extern "C" void kernel_launch(void* const* d_in, const int* in_sizes, int n_in,
                              void* d_out, int out_size, void* d_ws, size_t ws_size,
                              hipStream_t stream) {
    const float* y_soft = (const float*)d_in[0];
    const int* y_true  = (const int*)d_in[1];
    const int* mask    = (const int*)d_in[2];
    const int* edge    = (const int*)d_in[3];

    const int NC = in_sizes[0];          // N * C
    const int Nn = NC / NCLS;            // N
    const int L  = in_sizes[1];
    const int E  = in_sizes[3] / 2;

    const int* row = edge;               // source
    const int* col = edge + E;           // target

    float* vA = (float*)d_out;           // ping buffer (also final output)

    // ---- workspace layout (256B-aligned offsets) ----
    char* ws = (char*)d_ws;
    size_t off = 0;
    auto alloc = [&](size_t bytes) { char* p = ws + off; off += (bytes + 255) & ~(size_t)255; return p; };
    float* vB      = (float*)alloc((size_t)NC * 4);    // 25.6 MB
    __half* res_h  = (__half*)alloc((size_t)NC * 2);   // 12.8 MB
    int*   src     = (int*)alloc((size_t)E * 4);       // 12.8 MB
    int*   deg     = (int*)alloc((size_t)Nn * 4);
    int*   rowptr  = (int*)alloc((size_t)Nn * 4);
    int*   cursor  = (int*)alloc((size_t)Nn * 4);
    float* dinv    = (float*)alloc((size_t)Nn * 4);
    int*   winner  = (int*)alloc((size_t)Nn * 4);
    int*   bsum    = (int*)alloc((size_t)SCAN_BS * 4);

    const int NB = (Nn + SCAN_CHUNK - 1) / SCAN_CHUNK; // blocks for scan (<=256)

    hipMemsetAsync(deg, 0, (size_t)Nn * 4, stream);
    hipMemsetAsync(winner, 0xFF, (size_t)Nn * 4, stream);  // -1

    // CSR build
    deg_k<<<2048, 256, 0, stream>>>(col, deg, E);
    dinv_k<<<(Nn + 255) / 256, 256, 0, stream>>>(deg, dinv, Nn);
    scan_local_k<<<NB, SCAN_BS, 0, stream>>>(deg, rowptr, bsum, Nn);
    scan_bsum_k<<<1, SCAN_BS, 0, stream>>>(bsum, NB);
    scan_add_k<<<(Nn + 255) / 256, 256, 0, stream>>>(rowptr, bsum, Nn);
    copy_int_k<<<(Nn + 255) / 256, 256, 0, stream>>>(rowptr, cursor, Nn);
    scatter_k<<<2048, 256, 0, stream>>>(row, col, cursor, src, E);

    // Initial state: u = clamp(softmax(y)); res = (1-a)*u; v0 = dinv*u  (in d_out)
    softmax_k<<<2048, 256, 0, stream>>>(y_soft, vA, Nn);
    winner_k<<<(L + 255) / 256, 256, 0, stream>>>(mask, winner, L);
    clamp_k<<<(L * NCLS + 255) / 256, 256, 0, stream>>>(mask, y_true, winner, vA, L);
    vres_k<<<2048, 256, 0, stream>>>(dinv, vA, res_h, NC);

    // 10 fused pull+update iterations, ping-pong vA <-> vB; last writes u into d_out.
    const int pull_blocks = (Nn * NCLS + 255) / 256;
    for (int it = 0; it < 10; ++it) {
        const float* vin = (it & 1) ? vB : vA;
        float* vout      = (it & 1) ? vA : vB;
        pull_k<<<pull_blocks, 256, 0, stream>>>(rowptr, deg, src, dinv,
                                                vin, res_h, vout, Nn, it == 9);
    }
}

// Round 3
// 1326.343 us; speedup vs baseline: 5.2597x; 1.2264x over previous
//
#include <hip/hip_runtime.h>
#include <hip/hip_fp16.h>

#define NCLS 64
#define ALPHA 0.9f
#define SCAN_BS 256
#define SCAN_CHUNK 1024   // SCAN_BS * 4 items/thread
#define NBUCK 256
#define BSHIFT 9          // bucket = col >> 9 (512 nodes/bucket, Nn <= 131072)
#define BSPAN 512
#define P1_CAP 3200       // max edges per pass-1 block chunk (25.6 KB LDS)

__device__ __forceinline__ float wave_max64(float v) {
    #pragma unroll
    for (int o = 32; o > 0; o >>= 1) v = fmaxf(v, __shfl_xor(v, o, 64));
    return v;
}
__device__ __forceinline__ float wave_sum64(float v) {
    #pragma unroll
    for (int o = 32; o > 0; o >>= 1) v += __shfl_xor(v, o, 64);
    return v;
}

// One 64-lane wave per row: softmax over C=64 classes.
__global__ void softmax_k(const float* __restrict__ y, float* __restrict__ u, int n_nodes) {
    int lane = threadIdx.x & 63;
    int wave = (blockIdx.x * blockDim.x + threadIdx.x) >> 6;
    int nwaves = (gridDim.x * blockDim.x) >> 6;
    for (int n = wave; n < n_nodes; n += nwaves) {
        float v = y[(size_t)n * NCLS + lane];
        float m = wave_max64(v);
        float e = expf(v - m);
        float s = wave_sum64(e);
        u[(size_t)n * NCLS + lane] = e / s;
    }
}

// Deterministic "last write wins": winner[node] = max index i with mask[i]==node.
__global__ void winner_k(const int* __restrict__ mask, int* __restrict__ winner, int L) {
    int i = blockIdx.x * blockDim.x + threadIdx.x;
    if (i < L) atomicMax(&winner[mask[i]], i);
}

__global__ void deg_k(const int* __restrict__ col, int* __restrict__ deg, int E) {
    int stride = gridDim.x * blockDim.x;
    for (int e = blockIdx.x * blockDim.x + threadIdx.x; e < E; e += stride)
        atomicAdd(&deg[col[e]], 1);
}

__global__ void dinv_k(const int* __restrict__ deg, float* __restrict__ dinv, int n_nodes) {
    int i = blockIdx.x * blockDim.x + threadIdx.x;
    if (i < n_nodes) {
        int d = deg[i];
        dinv[i] = (d > 0) ? rsqrtf((float)d) : 0.0f;
    }
}

// ---- exclusive scan of deg -> rowptr ----
__global__ void scan_local_k(const int* __restrict__ deg, int* __restrict__ rowptr,
                             int* __restrict__ bsum, int n) {
    __shared__ int lds[SCAN_BS];
    int base = blockIdx.x * SCAN_CHUNK;
    int t = threadIdx.x;
    int v[4];
    int s = 0;
    #pragma unroll
    for (int k = 0; k < 4; ++k) {
        int i = base + t * 4 + k;
        v[k] = (i < n) ? deg[i] : 0;
        s += v[k];
    }
    lds[t] = s;
    __syncthreads();
    for (int o = 1; o < SCAN_BS; o <<= 1) {
        int x = (t >= o) ? lds[t - o] : 0;
        __syncthreads();
        lds[t] += x;
        __syncthreads();
    }
    int ex = (t > 0) ? lds[t - 1] : 0;
    #pragma unroll
    for (int k = 0; k < 4; ++k) {
        int i = base + t * 4 + k;
        if (i < n) rowptr[i] = ex;
        ex += v[k];
    }
    if (t == SCAN_BS - 1) bsum[blockIdx.x] = lds[t];
}

__global__ void scan_bsum_k(int* __restrict__ bsum, int nb) {
    __shared__ int lds[SCAN_BS];
    int t = threadIdx.x;
    int v = (t < nb) ? bsum[t] : 0;
    lds[t] = v;
    __syncthreads();
    for (int o = 1; o < SCAN_BS; o <<= 1) {
        int x = (t >= o) ? lds[t - o] : 0;
        __syncthreads();
        lds[t] += x;
        __syncthreads();
    }
    if (t < nb) bsum[t] = lds[t] - v;   // exclusive
}

__global__ void scan_add_k(int* __restrict__ rowptr, const int* __restrict__ bsum, int n) {
    int i = blockIdx.x * blockDim.x + threadIdx.x;
    if (i < n) rowptr[i] += bsum[i / SCAN_CHUNK];
}

// bucket cursor init: region base of bucket b is rowptr[b*BSPAN] (CSR order == bucket order)
__global__ void bcur_init_k(const int* __restrict__ rowptr, int* __restrict__ bcur,
                            int Nn, int E) {
    int b = threadIdx.x;
    int n = b * BSPAN;
    bcur[b] = (n < Nn) ? rowptr[n] : E;
}

// Pass 1: bin edges into NBUCK coarse buckets; coalesced copy-out via LDS staging.
__global__ void binpass1_k(const int* __restrict__ row, const int* __restrict__ col,
                           int* __restrict__ bcur, uint2* __restrict__ bpairs,
                           int E, int chunk) {
    __shared__ int hist[NBUCK];
    __shared__ int scn[NBUCK];
    __shared__ int lbase[NBUCK];
    __shared__ int lcur[NBUCK];
    __shared__ uint2 pairs[P1_CAP];
    int t = threadIdx.x;
    int e0 = blockIdx.x * chunk;
    int e1 = min(e0 + chunk, E);
    if (e0 >= E) return;
    hist[t] = 0;
    __syncthreads();
    for (int e = e0 + t; e < e1; e += 256)
        atomicAdd(&hist[col[e] >> BSHIFT], 1);
    __syncthreads();
    scn[t] = hist[t];
    __syncthreads();
    for (int o = 1; o < 256; o <<= 1) {
        int y = (t >= o) ? scn[t - o] : 0;
        __syncthreads();
        scn[t] += y;
        __syncthreads();
    }
    int cnt = hist[t];
    int lstart = scn[t] - cnt;            // exclusive local start
    int gb = 0;
    if (cnt > 0) gb = atomicAdd(&bcur[t], cnt);
    lbase[t] = gb - lstart;               // LDS slot i of bucket t -> global lbase[t]+i
    lcur[t] = lstart;
    __syncthreads();
    for (int e = e0 + t; e < e1; e += 256) {
        int c = col[e];
        int b = c >> BSHIFT;
        int p = atomicAdd(&lcur[b], 1);
        pairs[p] = make_uint2((unsigned)row[e], (unsigned)c);
    }
    __syncthreads();
    int n = e1 - e0;
    for (int i = t; i < n; i += 256) {
        uint2 pr = pairs[i];
        int b = (int)(pr.y >> BSHIFT);
        bpairs[lbase[b] + i] = pr;
    }
}

// Pass 2: one block per bucket; LDS per-node cursors; src writes stay in a ~65KB window.
__global__ void binpass2_k(const int* __restrict__ rowptr, const uint2* __restrict__ bpairs,
                           int* __restrict__ src, int Nn, int E) {
    __shared__ int cur[BSPAN];
    int b = blockIdx.x;
    int nb0 = b * BSPAN;
    if (nb0 >= Nn) return;
    int nb1 = min(nb0 + BSPAN, Nn);
    int t = threadIdx.x;
    for (int i = nb0 + t; i < nb1; i += 256) cur[i - nb0] = rowptr[i];
    __syncthreads();
    int e0 = rowptr[nb0];
    int e1 = (nb1 < Nn) ? rowptr[nb1] : E;
    for (int e = e0 + t; e < e1; e += 256) {
        uint2 pr = bpairs[e];
        int p = atomicAdd(&cur[(int)pr.y - nb0], 1);
        src[p] = (int)pr.x;
    }
}

// res_h = (1-a)*u0 (fp16), vh = dinv*u0 (fp16); u0 = onehot for labeled (clamp fused).
__global__ void vres_k(const float* __restrict__ dinv, const float* __restrict__ u,
                       const int* __restrict__ winner, const int* __restrict__ ytrue,
                       __half* __restrict__ res_h, __half* __restrict__ vh, int nc) {
    int stride = gridDim.x * blockDim.x;
    for (int i = blockIdx.x * blockDim.x + threadIdx.x; i < nc; i += stride) {
        int n = i >> 6;
        int lane = i & 63;
        int w = winner[n];
        float uu = (w >= 0) ? ((lane == ytrue[w]) ? 1.0f : 0.0f) : u[i];
        res_h[i] = __float2half((1.0f - ALPHA) * uu);
        vh[i] = __float2half(dinv[n] * uu);
    }
}

// Fused pull + update: one wave per node, lane = class. fp16 state.
__global__ void pull_k(const int* __restrict__ rowptr, const int* __restrict__ deg,
                       const int* __restrict__ src, const float* __restrict__ dinv,
                       const __half* __restrict__ vin, const __half* __restrict__ res_h,
                       __half* __restrict__ vout, float* __restrict__ uout,
                       int n_nodes, int last) {
    int lane = threadIdx.x & 63;
    int n = (blockIdx.x * blockDim.x + threadIdx.x) >> 6;
    if (n >= n_nodes) return;
    int start = rowptr[n];
    int len = deg[n];
    float acc0 = 0.0f, acc1 = 0.0f;
    for (int base = 0; base < len; base += 64) {
        int m = min(64, len - base);
        int sv = (lane < m) ? src[start + base + lane] : 0;
        int j = 0;
        for (; j + 2 <= m; j += 2) {
            int s0 = __shfl(sv, j, 64);
            int s1 = __shfl(sv, j + 1, 64);
            acc0 += __half2float(vin[(size_t)s0 * NCLS + lane]);
            acc1 += __half2float(vin[(size_t)s1 * NCLS + lane]);
        }
        if (j < m) {
            int s0 = __shfl(sv, j, 64);
            acc0 += __half2float(vin[(size_t)s0 * NCLS + lane]);
        }
    }
    float di = dinv[n];
    float u = ALPHA * (di * (acc0 + acc1)) + __half2float(res_h[(size_t)n * NCLS + lane]);
    u = fminf(fmaxf(u, 0.0f), 1.0f);
    if (last) uout[(size_t)n * NCLS + lane] = u;
    else      vout[(size_t)n * NCLS + lane] = __float2half(di * u);
}

extern "C" void kernel_launch(void* const* d_in, const int* in_sizes, int n_in,
                              void* d_out, int out_size, void* d_ws, size_t ws_size,
                              hipStream_t stream) {
    const float* y_soft = (const float*)d_in[0];
    const int* y_true  = (const int*)d_in[1];
    const int* mask    = (const int*)d_in[2];
    const int* edge    = (const int*)d_in[3];

    const int NC = in_sizes[0];          // N * C
    const int Nn = NC / NCLS;            // N
    const int L  = in_sizes[1];
    const int E  = in_sizes[3] / 2;

    const int* row = edge;               // source
    const int* col = edge + E;           // target

    float* u32 = (float*)d_out;          // fp32 u scratch + final output

    // ---- workspace layout (256B-aligned) ----
    char* ws = (char*)d_ws;
    size_t off = 0;
    auto alloc = [&](size_t bytes) { char* p = ws + off; off += (bytes + 255) & ~(size_t)255; return p; };
    // region0: bpairs (setup only) overlaps vhA+vhB (loop only)
    size_t reg0 = (size_t)E * 8;
    size_t vh_bytes = (size_t)NC * 2;
    if (2 * vh_bytes > reg0) reg0 = 2 * vh_bytes;
    char* region0 = alloc(reg0);
    uint2* bpairs = (uint2*)region0;
    __half* vhA   = (__half*)region0;
    __half* vhB   = (__half*)(region0 + vh_bytes);
    __half* res_h = (__half*)alloc((size_t)NC * 2);
    int*   src    = (int*)alloc((size_t)E * 4);
    int*   deg    = (int*)alloc((size_t)Nn * 4);
    int*   rowptr = (int*)alloc((size_t)Nn * 4);
    float* dinv   = (float*)alloc((size_t)Nn * 4);
    int*   winner = (int*)alloc((size_t)Nn * 4);
    int*   bcur   = (int*)alloc((size_t)NBUCK * 4);
    int*   bsum   = (int*)alloc((size_t)SCAN_BS * 4);

    const int NB = (Nn + SCAN_CHUNK - 1) / SCAN_CHUNK;

    hipMemsetAsync(deg, 0, (size_t)Nn * 4, stream);
    hipMemsetAsync(winner, 0xFF, (size_t)Nn * 4, stream);  // -1

    // CSR build
    deg_k<<<2048, 256, 0, stream>>>(col, deg, E);
    dinv_k<<<(Nn + 255) / 256, 256, 0, stream>>>(deg, dinv, Nn);
    scan_local_k<<<NB, SCAN_BS, 0, stream>>>(deg, rowptr, bsum, Nn);
    scan_bsum_k<<<1, SCAN_BS, 0, stream>>>(bsum, NB);
    scan_add_k<<<(Nn + 255) / 256, 256, 0, stream>>>(rowptr, bsum, Nn);
    bcur_init_k<<<1, NBUCK, 0, stream>>>(rowptr, bcur, Nn, E);

    // Two-pass bucketed counting sort
    const int chunk = P1_CAP;
    const int nchunks = (E + chunk - 1) / chunk;
    binpass1_k<<<nchunks, 256, 0, stream>>>(row, col, bcur, bpairs, E, chunk);
    binpass2_k<<<(Nn + BSPAN - 1) / BSPAN, 256, 0, stream>>>(rowptr, bpairs, src, Nn, E);

    // Initial state (bpairs region is dead after binpass2; vhA/vhB take it over)
    softmax_k<<<2048, 256, 0, stream>>>(y_soft, u32, Nn);
    winner_k<<<(L + 255) / 256, 256, 0, stream>>>(mask, winner, L);
    vres_k<<<2048, 256, 0, stream>>>(dinv, u32, winner, y_true, res_h, vhA, NC);

    // 10 fused pull+update iterations, fp16 ping-pong; last writes fp32 into d_out.
    const int pull_blocks = (Nn * NCLS + 255) / 256;
    for (int it = 0; it < 10; ++it) {
        const __half* vin = (it & 1) ? vhB : vhA;
        __half* vout      = (it & 1) ? vhA : vhB;
        pull_k<<<pull_blocks, 256, 0, stream>>>(rowptr, deg, src, dinv,
                                                vin, res_h, vout, u32, Nn, it == 9);
    }
}

// Round 5
// 955.037 us; speedup vs baseline: 7.3046x; 1.3888x over previous
//
#include <hip/hip_runtime.h>
#include <hip/hip_fp16.h>

#define NCLS 64
#define ALPHA 0.9f
#define SCAN_BS 256
#define SCAN_CHUNK 1024   // SCAN_BS * 4 items/thread
#define NBUCK 256
#define BSHIFT 9          // bucket = col >> 9 (512 nodes/bucket, Nn <= 131072)
#define BSPAN 512
#define P1_CAP 3200       // max edges per pass-1 block chunk (25.6 KB LDS)

__device__ __forceinline__ float wave_max64(float v) {
    #pragma unroll
    for (int o = 32; o > 0; o >>= 1) v = fmaxf(v, __shfl_xor(v, o, 64));
    return v;
}
__device__ __forceinline__ float wave_sum64(float v) {
    #pragma unroll
    for (int o = 32; o > 0; o >>= 1) v += __shfl_xor(v, o, 64);
    return v;
}

// Deterministic "last write wins": winner[node] = max index i with mask[i]==node.
__global__ void winner_k(const int* __restrict__ mask, int* __restrict__ winner, int L) {
    int i = blockIdx.x * blockDim.x + threadIdx.x;
    if (i < L) atomicMax(&winner[mask[i]], i);
}

__global__ void deg_k(const int* __restrict__ col, int* __restrict__ deg, int E) {
    int stride = gridDim.x * blockDim.x;
    for (int e = blockIdx.x * blockDim.x + threadIdx.x; e < E; e += stride)
        atomicAdd(&deg[col[e]], 1);
}

__global__ void dinv_k(const int* __restrict__ deg, float* __restrict__ dinv, int n_nodes) {
    int i = blockIdx.x * blockDim.x + threadIdx.x;
    if (i < n_nodes) {
        int d = deg[i];
        dinv[i] = (d > 0) ? rsqrtf((float)d) : 0.0f;
    }
}

// ---- exclusive scan of deg -> rowptr ----
__global__ void scan_local_k(const int* __restrict__ deg, int* __restrict__ rowptr,
                             int* __restrict__ bsum, int n) {
    __shared__ int lds[SCAN_BS];
    int base = blockIdx.x * SCAN_CHUNK;
    int t = threadIdx.x;
    int v[4];
    int s = 0;
    #pragma unroll
    for (int k = 0; k < 4; ++k) {
        int i = base + t * 4 + k;
        v[k] = (i < n) ? deg[i] : 0;
        s += v[k];
    }
    lds[t] = s;
    __syncthreads();
    for (int o = 1; o < SCAN_BS; o <<= 1) {
        int x = (t >= o) ? lds[t - o] : 0;
        __syncthreads();
        lds[t] += x;
        __syncthreads();
    }
    int ex = (t > 0) ? lds[t - 1] : 0;
    #pragma unroll
    for (int k = 0; k < 4; ++k) {
        int i = base + t * 4 + k;
        if (i < n) rowptr[i] = ex;
        ex += v[k];
    }
    if (t == SCAN_BS - 1) bsum[blockIdx.x] = lds[t];
}

__global__ void scan_bsum_k(int* __restrict__ bsum, int nb) {
    __shared__ int lds[SCAN_BS];
    int t = threadIdx.x;
    int v = (t < nb) ? bsum[t] : 0;
    lds[t] = v;
    __syncthreads();
    for (int o = 1; o < SCAN_BS; o <<= 1) {
        int x = (t >= o) ? lds[t - o] : 0;
        __syncthreads();
        lds[t] += x;
        __syncthreads();
    }
    if (t < nb) bsum[t] = lds[t] - v;   // exclusive
}

__global__ void scan_add_k(int* __restrict__ rowptr, const int* __restrict__ bsum, int n) {
    int i = blockIdx.x * blockDim.x + threadIdx.x;
    if (i < n) rowptr[i] += bsum[i / SCAN_CHUNK];
}

// bucket cursor init: region base of bucket b is rowptr[b*BSPAN] (CSR order == bucket order)
__global__ void bcur_init_k(const int* __restrict__ rowptr, int* __restrict__ bcur,
                            int Nn, int E) {
    int b = threadIdx.x;
    int n = b * BSPAN;
    bcur[b] = (n < Nn) ? rowptr[n] : E;
}

// Pass 1: bin edges into NBUCK coarse buckets; coalesced copy-out via LDS staging.
__global__ void binpass1_k(const int* __restrict__ row, const int* __restrict__ col,
                           int* __restrict__ bcur, uint2* __restrict__ bpairs,
                           int E, int chunk) {
    __shared__ int hist[NBUCK];
    __shared__ int scn[NBUCK];
    __shared__ int lbase[NBUCK];
    __shared__ int lcur[NBUCK];
    __shared__ uint2 pairs[P1_CAP];
    int t = threadIdx.x;
    int e0 = blockIdx.x * chunk;
    int e1 = min(e0 + chunk, E);
    if (e0 >= E) return;
    hist[t] = 0;
    __syncthreads();
    for (int e = e0 + t; e < e1; e += 256)
        atomicAdd(&hist[col[e] >> BSHIFT], 1);
    __syncthreads();
    scn[t] = hist[t];
    __syncthreads();
    for (int o = 1; o < 256; o <<= 1) {
        int y = (t >= o) ? scn[t - o] : 0;
        __syncthreads();
        scn[t] += y;
        __syncthreads();
    }
    int cnt = hist[t];
    int lstart = scn[t] - cnt;            // exclusive local start
    int gb = 0;
    if (cnt > 0) gb = atomicAdd(&bcur[t], cnt);
    lbase[t] = gb - lstart;               // LDS slot i of bucket t -> global lbase[t]+i
    lcur[t] = lstart;
    __syncthreads();
    for (int e = e0 + t; e < e1; e += 256) {
        int c = col[e];
        int b = c >> BSHIFT;
        int p = atomicAdd(&lcur[b], 1);
        pairs[p] = make_uint2((unsigned)row[e], (unsigned)c);
    }
    __syncthreads();
    int n = e1 - e0;
    for (int i = t; i < n; i += 256) {
        uint2 pr = pairs[i];
        int b = (int)(pr.y >> BSHIFT);
        bpairs[lbase[b] + i] = pr;
    }
}

// Pass 2: one block per bucket; LDS per-node cursors; src writes stay in a ~65KB window.
__global__ void binpass2_k(const int* __restrict__ rowptr, const uint2* __restrict__ bpairs,
                           int* __restrict__ src, int Nn, int E) {
    __shared__ int cur[BSPAN];
    int b = blockIdx.x;
    int nb0 = b * BSPAN;
    if (nb0 >= Nn) return;
    int nb1 = min(nb0 + BSPAN, Nn);
    int t = threadIdx.x;
    for (int i = nb0 + t; i < nb1; i += 256) cur[i - nb0] = rowptr[i];
    __syncthreads();
    int e0 = rowptr[nb0];
    int e1 = (nb1 < Nn) ? rowptr[nb1] : E;
    for (int e = e0 + t; e < e1; e += 256) {
        uint2 pr = bpairs[e];
        int p = atomicAdd(&cur[(int)pr.y - nb0], 1);
        src[p] = (int)pr.x;
    }
}

// Fused softmax + one-hot clamp + res/v init. One wave per node, lane = class.
__global__ void init_k(const float* __restrict__ y, const int* __restrict__ winner,
                       const int* __restrict__ ytrue, const float* __restrict__ dinv,
                       __half* __restrict__ res_h, __half* __restrict__ vh, int Nn) {
    int lane = threadIdx.x & 63;
    int wave = (blockIdx.x * blockDim.x + threadIdx.x) >> 6;
    int nwaves = (gridDim.x * blockDim.x) >> 6;
    for (int n = wave; n < Nn; n += nwaves) {
        float v = y[(size_t)n * NCLS + lane];
        float m = wave_max64(v);
        float e = expf(v - m);
        float s = wave_sum64(e);
        float u = e / s;
        int w = winner[n];
        if (w >= 0) u = (lane == ytrue[w]) ? 1.0f : 0.0f;
        res_h[(size_t)n * NCLS + lane] = __float2half((1.0f - ALPHA) * u);
        vh[(size_t)n * NCLS + lane] = __float2half(dinv[n] * u);
    }
}

// Fused pull + update, half2 form: one wave per node; lane k<32 handles classes
// {2k,2k+1} from even edges, lanes 32-63 the same classes from odd edges;
// halves combined with one shfl_xor(32) at the end.
__global__ void pull_k(const int* __restrict__ rowptr, const int* __restrict__ deg,
                       const int* __restrict__ src, const float* __restrict__ dinv,
                       const __half2* __restrict__ vin2, const __half2* __restrict__ res2,
                       __half2* __restrict__ vout2, float2* __restrict__ uout2,
                       int n_nodes, int last) {
    int lane = threadIdx.x & 63;
    int half_id = lane >> 5;
    int k = lane & 31;
    int n = (blockIdx.x * blockDim.x + threadIdx.x) >> 6;
    if (n >= n_nodes) return;
    int start = rowptr[n];
    int len = deg[n];
    float2 a0 = make_float2(0.f, 0.f), a1 = make_float2(0.f, 0.f);
    float2 a2 = make_float2(0.f, 0.f), a3 = make_float2(0.f, 0.f);
    for (int base = 0; base < len; base += 64) {
        int m = min(64, len - base);
        int sv = (lane < m) ? __builtin_nontemporal_load(&src[start + base + lane]) : 0;
        int j = 0;
        for (; j + 8 <= m; j += 8) {
            int sA = __shfl(sv, j     + half_id, 64);
            int sB = __shfl(sv, j + 2 + half_id, 64);
            int sC = __shfl(sv, j + 4 + half_id, 64);
            int sD = __shfl(sv, j + 6 + half_id, 64);
            float2 fA = __half22float2(vin2[(size_t)sA * 32 + k]);
            float2 fB = __half22float2(vin2[(size_t)sB * 32 + k]);
            float2 fC = __half22float2(vin2[(size_t)sC * 32 + k]);
            float2 fD = __half22float2(vin2[(size_t)sD * 32 + k]);
            a0.x += fA.x; a0.y += fA.y;
            a1.x += fB.x; a1.y += fB.y;
            a2.x += fC.x; a2.y += fC.y;
            a3.x += fD.x; a3.y += fD.y;
        }
        for (; j + 2 <= m; j += 2) {
            int sA = __shfl(sv, j + half_id, 64);
            float2 fA = __half22float2(vin2[(size_t)sA * 32 + k]);
            a0.x += fA.x; a0.y += fA.y;
        }
        if (j < m) {
            int sA = __shfl(sv, j, 64);
            float2 fA = __half22float2(vin2[(size_t)sA * 32 + k]);
            if (half_id == 0) { a0.x += fA.x; a0.y += fA.y; }
        }
    }
    float sx = (a0.x + a1.x) + (a2.x + a3.x);
    float sy = (a0.y + a1.y) + (a2.y + a3.y);
    sx += __shfl_xor(sx, 32, 64);
    sy += __shfl_xor(sy, 32, 64);
    float di = dinv[n];
    unsigned rraw = __builtin_nontemporal_load(
        reinterpret_cast<const unsigned*>(&res2[(size_t)n * 32 + k]));
    union { unsigned u; __half2 h; } cv; cv.u = rraw;
    float2 r = __half22float2(cv.h);
    float u0 = fminf(fmaxf(ALPHA * (di * sx) + r.x, 0.0f), 1.0f);
    float u1 = fminf(fmaxf(ALPHA * (di * sy) + r.y, 0.0f), 1.0f);
    if (lane < 32) {
        size_t idx = (size_t)n * 32 + k;
        if (last) uout2[idx] = make_float2(u0, u1);
        else      vout2[idx] = __floats2half2_rn(di * u0, di * u1);
    }
}

extern "C" void kernel_launch(void* const* d_in, const int* in_sizes, int n_in,
                              void* d_out, int out_size, void* d_ws, size_t ws_size,
                              hipStream_t stream) {
    const float* y_soft = (const float*)d_in[0];
    const int* y_true  = (const int*)d_in[1];
    const int* mask    = (const int*)d_in[2];
    const int* edge    = (const int*)d_in[3];

    const int NC = in_sizes[0];          // N * C
    const int Nn = NC / NCLS;            // N
    const int L  = in_sizes[1];
    const int E  = in_sizes[3] / 2;

    const int* row = edge;               // source
    const int* col = edge + E;           // target

    float2* uout2 = (float2*)d_out;      // final fp32 output

    // ---- workspace layout (256B-aligned) ----
    char* ws = (char*)d_ws;
    size_t off = 0;
    auto alloc = [&](size_t bytes) { char* p = ws + off; off += (bytes + 255) & ~(size_t)255; return p; };
    // region0: bpairs (setup only) overlaps vhA+vhB (loop only)
    size_t reg0 = (size_t)E * 8;
    size_t vh_bytes = (size_t)NC * 2;
    if (2 * vh_bytes > reg0) reg0 = 2 * vh_bytes;
    char* region0 = alloc(reg0);
    uint2* bpairs = (uint2*)region0;
    __half* vhA   = (__half*)region0;
    __half* vhB   = (__half*)(region0 + vh_bytes);
    __half* res_h = (__half*)alloc((size_t)NC * 2);
    int*   src    = (int*)alloc((size_t)E * 4);
    int*   deg    = (int*)alloc((size_t)Nn * 4);
    int*   rowptr = (int*)alloc((size_t)Nn * 4);
    float* dinv   = (float*)alloc((size_t)Nn * 4);
    int*   winner = (int*)alloc((size_t)Nn * 4);
    int*   bcur   = (int*)alloc((size_t)NBUCK * 4);
    int*   bsum   = (int*)alloc((size_t)SCAN_BS * 4);

    const int NB = (Nn + SCAN_CHUNK - 1) / SCAN_CHUNK;

    hipMemsetAsync(deg, 0, (size_t)Nn * 4, stream);
    hipMemsetAsync(winner, 0xFF, (size_t)Nn * 4, stream);  // -1

    // CSR build (round-3 proven pipeline)
    deg_k<<<2048, 256, 0, stream>>>(col, deg, E);
    dinv_k<<<(Nn + 255) / 256, 256, 0, stream>>>(deg, dinv, Nn);
    scan_local_k<<<NB, SCAN_BS, 0, stream>>>(deg, rowptr, bsum, Nn);
    scan_bsum_k<<<1, SCAN_BS, 0, stream>>>(bsum, NB);
    scan_add_k<<<(Nn + 255) / 256, 256, 0, stream>>>(rowptr, bsum, Nn);
    bcur_init_k<<<1, NBUCK, 0, stream>>>(rowptr, bcur, Nn, E);
    const int chunk = P1_CAP;
    const int nchunks = (E + chunk - 1) / chunk;
    binpass1_k<<<nchunks, 256, 0, stream>>>(row, col, bcur, bpairs, E, chunk);
    binpass2_k<<<(Nn + BSPAN - 1) / BSPAN, 256, 0, stream>>>(rowptr, bpairs, src, Nn, E);

    // Initial state (bpairs region is dead after binpass2; vhA/vhB take it over)
    winner_k<<<(L + 255) / 256, 256, 0, stream>>>(mask, winner, L);
    init_k<<<2048, 256, 0, stream>>>(y_soft, winner, y_true, dinv, res_h, vhA, Nn);

    // 10 fused pull+update iterations, fp16 ping-pong; last writes fp32 into d_out.
    const int pull_blocks = (Nn * NCLS + 255) / 256;
    for (int it = 0; it < 10; ++it) {
        const __half2* vin2 = (const __half2*)((it & 1) ? vhB : vhA);
        __half2* vout2      = (__half2*)((it & 1) ? vhA : vhB);
        pull_k<<<pull_blocks, 256, 0, stream>>>(rowptr, deg, src, dinv,
                                                vin2, (const __half2*)res_h,
                                                vout2, uout2, Nn, it == 9);
    }
}

// Round 6
// 863.681 us; speedup vs baseline: 8.0772x; 1.1058x over previous
//
#include <hip/hip_runtime.h>
#include <hip/hip_fp16.h>

#define NCLS 64
#define ALPHA 0.9f
#define SCAN_BS 256
#define SCAN_CHUNK 1024   // SCAN_BS * 4 items/thread
#define NBUCK 256
#define BSHIFT 9          // bucket = col >> 9 (512 nodes/bucket, Nn <= 131072)
#define BSPAN 512
#define P1_CAP 3200       // max edges per pass-1 block chunk
#define ROWMASK 0x7FFFFFu // low 23 bits = row id (requires Nn < 2^23)

__device__ __forceinline__ float wave_max64(float v) {
    #pragma unroll
    for (int o = 32; o > 0; o >>= 1) v = fmaxf(v, __shfl_xor(v, o, 64));
    return v;
}
__device__ __forceinline__ float wave_sum64(float v) {
    #pragma unroll
    for (int o = 32; o > 0; o >>= 1) v += __shfl_xor(v, o, 64);
    return v;
}

// Deterministic "last write wins": winner[node] = max index i with mask[i]==node.
__global__ void winner_k(const int* __restrict__ mask, int* __restrict__ winner, int L) {
    int i = blockIdx.x * blockDim.x + threadIdx.x;
    if (i < L) atomicMax(&winner[mask[i]], i);
}

// Coarse 256-bucket histogram of col>>BSHIFT via LDS privatization.
__global__ void bcount_k(const int* __restrict__ col, int* __restrict__ bcnt, int E) {
    __shared__ int h[NBUCK];
    int t = threadIdx.x;
    h[t] = 0;
    __syncthreads();
    int stride = gridDim.x * blockDim.x;
    for (int e = blockIdx.x * blockDim.x + t; e < E; e += stride)
        atomicAdd(&h[col[e] >> BSHIFT], 1);
    __syncthreads();
    if (h[t]) atomicAdd(&bcnt[t], h[t]);
}

// Exclusive scan of bucket counts -> bbase[257]; bcur = bbase.
__global__ void bscan_k(const int* __restrict__ bcnt, int* __restrict__ bbase,
                        int* __restrict__ bcur, int E) {
    __shared__ int lds[NBUCK];
    int t = threadIdx.x;
    int v = bcnt[t];
    lds[t] = v;
    __syncthreads();
    for (int o = 1; o < NBUCK; o <<= 1) {
        int x = (t >= o) ? lds[t - o] : 0;
        __syncthreads();
        lds[t] += x;
        __syncthreads();
    }
    int ex = lds[t] - v;
    bbase[t] = ex;
    bcur[t] = ex;
    if (t == NBUCK - 1) bbase[NBUCK] = E;
}

// Pass 1: bin edges into NBUCK coarse buckets; coalesced copy-out via LDS staging.
// Each staged edge is packed: (col & 511) << 23 | row.
__global__ void binpass1_k(const int* __restrict__ row, const int* __restrict__ col,
                           int* __restrict__ bcur, unsigned* __restrict__ bpk,
                           int E, int chunk) {
    __shared__ int hist[NBUCK];
    __shared__ int scn[NBUCK];
    __shared__ int lbase[NBUCK];
    __shared__ int lcur[NBUCK];
    __shared__ unsigned pay[P1_CAP];
    __shared__ unsigned char bkt[P1_CAP];
    int t = threadIdx.x;
    int e0 = blockIdx.x * chunk;
    int e1 = min(e0 + chunk, E);
    if (e0 >= E) return;
    hist[t] = 0;
    __syncthreads();
    for (int e = e0 + t; e < e1; e += 256)
        atomicAdd(&hist[col[e] >> BSHIFT], 1);
    __syncthreads();
    scn[t] = hist[t];
    __syncthreads();
    for (int o = 1; o < 256; o <<= 1) {
        int y = (t >= o) ? scn[t - o] : 0;
        __syncthreads();
        scn[t] += y;
        __syncthreads();
    }
    int cnt = hist[t];
    int lstart = scn[t] - cnt;            // exclusive local start
    int gb = 0;
    if (cnt > 0) gb = atomicAdd(&bcur[t], cnt);
    lbase[t] = gb - lstart;               // LDS slot i of bucket t -> global lbase[t]+i
    lcur[t] = lstart;
    __syncthreads();
    for (int e = e0 + t; e < e1; e += 256) {
        int c = col[e];
        int b = c >> BSHIFT;
        int p = atomicAdd(&lcur[b], 1);
        pay[p] = ((unsigned)(c & (BSPAN - 1)) << 23) | (unsigned)row[e];
        bkt[p] = (unsigned char)b;
    }
    __syncthreads();
    int n = e1 - e0;
    for (int i = t; i < n; i += 256) {
        unsigned w = pay[i];
        int b = bkt[i];
        bpk[lbase[b] + i] = w;
    }
}

// Per-bucket LDS histogram over sorted packed pairs -> deg + dinv (replaces deg_k).
__global__ void bdeg_k(const int* __restrict__ bbase, const unsigned* __restrict__ bpk,
                       int* __restrict__ deg, float* __restrict__ dinv, int Nn) {
    __shared__ int hist[BSPAN];
    int b = blockIdx.x;
    int nb0 = b * BSPAN;
    if (nb0 >= Nn) return;
    int t = threadIdx.x;
    hist[t] = 0;
    hist[t + 256] = 0;
    __syncthreads();
    int e0 = bbase[b];
    int e1 = bbase[b + 1];
    for (int e = e0 + t; e < e1; e += 256)
        atomicAdd(&hist[bpk[e] >> 23], 1);
    __syncthreads();
    int n0 = nb0 + t;
    if (n0 < Nn) {
        int d = hist[t];
        deg[n0] = d;
        dinv[n0] = (d > 0) ? rsqrtf((float)d) : 0.0f;
    }
    int n1 = nb0 + 256 + t;
    if (n1 < Nn) {
        int d = hist[t + 256];
        deg[n1] = d;
        dinv[n1] = (d > 0) ? rsqrtf((float)d) : 0.0f;
    }
}

// ---- exclusive scan of deg -> rowptr (proven pipeline) ----
__global__ void scan_local_k(const int* __restrict__ deg, int* __restrict__ rowptr,
                             int* __restrict__ bsum, int n) {
    __shared__ int lds[SCAN_BS];
    int base = blockIdx.x * SCAN_CHUNK;
    int t = threadIdx.x;
    int v[4];
    int s = 0;
    #pragma unroll
    for (int k = 0; k < 4; ++k) {
        int i = base + t * 4 + k;
        v[k] = (i < n) ? deg[i] : 0;
        s += v[k];
    }
    lds[t] = s;
    __syncthreads();
    for (int o = 1; o < SCAN_BS; o <<= 1) {
        int x = (t >= o) ? lds[t - o] : 0;
        __syncthreads();
        lds[t] += x;
        __syncthreads();
    }
    int ex = (t > 0) ? lds[t - 1] : 0;
    #pragma unroll
    for (int k = 0; k < 4; ++k) {
        int i = base + t * 4 + k;
        if (i < n) rowptr[i] = ex;
        ex += v[k];
    }
    if (t == SCAN_BS - 1) bsum[blockIdx.x] = lds[t];
}

__global__ void scan_bsum_k(int* __restrict__ bsum, int nb) {
    __shared__ int lds[SCAN_BS];
    int t = threadIdx.x;
    int v = (t < nb) ? bsum[t] : 0;
    lds[t] = v;
    __syncthreads();
    for (int o = 1; o < SCAN_BS; o <<= 1) {
        int x = (t >= o) ? lds[t - o] : 0;
        __syncthreads();
        lds[t] += x;
        __syncthreads();
    }
    if (t < nb) bsum[t] = lds[t] - v;   // exclusive
}

__global__ void scan_add_k(int* __restrict__ rowptr, const int* __restrict__ bsum, int n) {
    int i = blockIdx.x * blockDim.x + threadIdx.x;
    if (i < n) rowptr[i] += bsum[i / SCAN_CHUNK];
}

// Pass 2 (r3-proven structure): one block per bucket; LDS per-node cursors from
// rowptr; src writes stay in a ~65KB L2-resident window. Packed-word decode.
__global__ void binpass2_k(const int* __restrict__ rowptr, const unsigned* __restrict__ bpk,
                           int* __restrict__ src, int Nn, int E) {
    __shared__ int cur[BSPAN];
    int b = blockIdx.x;
    int nb0 = b * BSPAN;
    if (nb0 >= Nn) return;
    int nb1 = min(nb0 + BSPAN, Nn);
    int t = threadIdx.x;
    for (int i = nb0 + t; i < nb1; i += 256) cur[i - nb0] = rowptr[i];
    __syncthreads();
    int e0 = rowptr[nb0];
    int e1 = (nb1 < Nn) ? rowptr[nb1] : E;
    for (int e = e0 + t; e < e1; e += 256) {
        unsigned w = bpk[e];
        int p = atomicAdd(&cur[w >> 23], 1);
        src[p] = (int)(w & ROWMASK);
    }
}

// Fused softmax + one-hot clamp + res/v init. One wave per node, lane = class.
__global__ void init_k(const float* __restrict__ y, const int* __restrict__ winner,
                       const int* __restrict__ ytrue, const float* __restrict__ dinv,
                       __half* __restrict__ res_h, __half* __restrict__ vh, int Nn) {
    int lane = threadIdx.x & 63;
    int wave = (blockIdx.x * blockDim.x + threadIdx.x) >> 6;
    int nwaves = (gridDim.x * blockDim.x) >> 6;
    for (int n = wave; n < Nn; n += nwaves) {
        float v = y[(size_t)n * NCLS + lane];
        float m = wave_max64(v);
        float e = expf(v - m);
        float s = wave_sum64(e);
        float u = e / s;
        int w = winner[n];
        if (w >= 0) u = (lane == ytrue[w]) ? 1.0f : 0.0f;
        res_h[(size_t)n * NCLS + lane] = __float2half((1.0f - ALPHA) * u);
        vh[(size_t)n * NCLS + lane] = __float2half(dinv[n] * u);
    }
}

// Fused pull + update, half2 form (proven r5): one wave per node; lane k<32
// handles classes {2k,2k+1} from even edges, lanes 32-63 from odd edges.
__global__ void pull_k(const int* __restrict__ rowptr, const int* __restrict__ deg,
                       const int* __restrict__ src, const float* __restrict__ dinv,
                       const __half2* __restrict__ vin2, const __half2* __restrict__ res2,
                       __half2* __restrict__ vout2, float2* __restrict__ uout2,
                       int n_nodes, int last) {
    int lane = threadIdx.x & 63;
    int half_id = lane >> 5;
    int k = lane & 31;
    int n = (blockIdx.x * blockDim.x + threadIdx.x) >> 6;
    if (n >= n_nodes) return;
    int start = rowptr[n];
    int len = deg[n];
    float2 a0 = make_float2(0.f, 0.f), a1 = make_float2(0.f, 0.f);
    float2 a2 = make_float2(0.f, 0.f), a3 = make_float2(0.f, 0.f);
    for (int base = 0; base < len; base += 64) {
        int m = min(64, len - base);
        int sv = (lane < m) ? __builtin_nontemporal_load(&src[start + base + lane]) : 0;
        int j = 0;
        for (; j + 8 <= m; j += 8) {
            int sA = __shfl(sv, j     + half_id, 64);
            int sB = __shfl(sv, j + 2 + half_id, 64);
            int sC = __shfl(sv, j + 4 + half_id, 64);
            int sD = __shfl(sv, j + 6 + half_id, 64);
            float2 fA = __half22float2(vin2[(size_t)sA * 32 + k]);
            float2 fB = __half22float2(vin2[(size_t)sB * 32 + k]);
            float2 fC = __half22float2(vin2[(size_t)sC * 32 + k]);
            float2 fD = __half22float2(vin2[(size_t)sD * 32 + k]);
            a0.x += fA.x; a0.y += fA.y;
            a1.x += fB.x; a1.y += fB.y;
            a2.x += fC.x; a2.y += fC.y;
            a3.x += fD.x; a3.y += fD.y;
        }
        for (; j + 2 <= m; j += 2) {
            int sA = __shfl(sv, j + half_id, 64);
            float2 fA = __half22float2(vin2[(size_t)sA * 32 + k]);
            a0.x += fA.x; a0.y += fA.y;
        }
        if (j < m) {
            int sA = __shfl(sv, j, 64);
            float2 fA = __half22float2(vin2[(size_t)sA * 32 + k]);
            if (half_id == 0) { a0.x += fA.x; a0.y += fA.y; }
        }
    }
    float sx = (a0.x + a1.x) + (a2.x + a3.x);
    float sy = (a0.y + a1.y) + (a2.y + a3.y);
    sx += __shfl_xor(sx, 32, 64);
    sy += __shfl_xor(sy, 32, 64);
    float di = dinv[n];
    unsigned rraw = __builtin_nontemporal_load(
        reinterpret_cast<const unsigned*>(&res2[(size_t)n * 32 + k]));
    union { unsigned u; __half2 h; } cv; cv.u = rraw;
    float2 r = __half22float2(cv.h);
    float u0 = fminf(fmaxf(ALPHA * (di * sx) + r.x, 0.0f), 1.0f);
    float u1 = fminf(fmaxf(ALPHA * (di * sy) + r.y, 0.0f), 1.0f);
    if (lane < 32) {
        size_t idx = (size_t)n * 32 + k;
        if (last) uout2[idx] = make_float2(u0, u1);
        else      vout2[idx] = __floats2half2_rn(di * u0, di * u1);
    }
}

extern "C" void kernel_launch(void* const* d_in, const int* in_sizes, int n_in,
                              void* d_out, int out_size, void* d_ws, size_t ws_size,
                              hipStream_t stream) {
    const float* y_soft = (const float*)d_in[0];
    const int* y_true  = (const int*)d_in[1];
    const int* mask    = (const int*)d_in[2];
    const int* edge    = (const int*)d_in[3];

    const int NC = in_sizes[0];          // N * C
    const int Nn = NC / NCLS;            // N
    const int L  = in_sizes[1];
    const int E  = in_sizes[3] / 2;

    const int* row = edge;               // source
    const int* col = edge + E;           // target

    float2* uout2 = (float2*)d_out;      // final fp32 output

    // ---- workspace layout (256B-aligned) ----
    char* ws = (char*)d_ws;
    size_t off = 0;
    auto alloc = [&](size_t bytes) { char* p = ws + off; off += (bytes + 255) & ~(size_t)255; return p; };
    // region0: bpk (setup only, E*4) overlaps vhA+vhB (loop only, NC*4)
    size_t reg0 = (size_t)E * 4;
    size_t vh_bytes = (size_t)NC * 2;
    if (2 * vh_bytes > reg0) reg0 = 2 * vh_bytes;
    char* region0 = alloc(reg0);
    unsigned* bpk = (unsigned*)region0;
    __half* vhA   = (__half*)region0;
    __half* vhB   = (__half*)(region0 + vh_bytes);
    __half* res_h = (__half*)alloc((size_t)NC * 2);
    int*   src    = (int*)alloc((size_t)E * 4);
    int*   deg    = (int*)alloc((size_t)Nn * 4);
    int*   rowptr = (int*)alloc((size_t)Nn * 4);
    float* dinv   = (float*)alloc((size_t)Nn * 4);
    int*   winner = (int*)alloc((size_t)Nn * 4);
    int*   bcnt   = (int*)alloc((size_t)NBUCK * 4);
    int*   bbase  = (int*)alloc((size_t)(NBUCK + 1) * 4);
    int*   bcur   = (int*)alloc((size_t)NBUCK * 4);
    int*   bsum   = (int*)alloc((size_t)SCAN_BS * 4);

    const int NB = (Nn + SCAN_CHUNK - 1) / SCAN_CHUNK;
    const int NBK = (Nn + BSPAN - 1) / BSPAN;

    hipMemsetAsync(winner, 0xFF, (size_t)Nn * 4, stream);  // -1
    hipMemsetAsync(bcnt, 0, (size_t)NBUCK * 4, stream);

    winner_k<<<(L + 255) / 256, 256, 0, stream>>>(mask, winner, L);

    // CSR build: coarse counts -> bucket bases -> sort pass 1 -> per-node deg ->
    // scan -> rowptr -> sort pass 2
    bcount_k<<<1024, 256, 0, stream>>>(col, bcnt, E);
    bscan_k<<<1, NBUCK, 0, stream>>>(bcnt, bbase, bcur, E);
    const int chunk = P1_CAP;
    const int nchunks = (E + chunk - 1) / chunk;
    binpass1_k<<<nchunks, 256, 0, stream>>>(row, col, bcur, bpk, E, chunk);
    bdeg_k<<<NBK, 256, 0, stream>>>(bbase, bpk, deg, dinv, Nn);
    scan_local_k<<<NB, SCAN_BS, 0, stream>>>(deg, rowptr, bsum, Nn);
    scan_bsum_k<<<1, SCAN_BS, 0, stream>>>(bsum, NB);
    scan_add_k<<<(Nn + 255) / 256, 256, 0, stream>>>(rowptr, bsum, Nn);
    binpass2_k<<<NBK, 256, 0, stream>>>(rowptr, bpk, src, Nn, E);

    // Initial state (bpk region is dead after binpass2; vhA/vhB take it over)
    init_k<<<2048, 256, 0, stream>>>(y_soft, winner, y_true, dinv, res_h, vhA, Nn);

    // 10 fused pull+update iterations, fp16 ping-pong; last writes fp32 into d_out.
    const int pull_blocks = (Nn * NCLS + 255) / 256;
    for (int it = 0; it < 10; ++it) {
        const __half2* vin2 = (const __half2*)((it & 1) ? vhB : vhA);
        __half2* vout2      = (__half2*)((it & 1) ? vhA : vhB);
        pull_k<<<pull_blocks, 256, 0, stream>>>(rowptr, deg, src, dinv,
                                                vin2, (const __half2*)res_h,
                                                vout2, uout2, Nn, it == 9);
    }
}